// Round 4
// baseline (207.500 us; speedup 1.0000x reference)
//
#include <hip/hip_runtime.h>
#include <stdint.h>
#include <stddef.h>

// CliffordLinear as one bf16 GEMM:
//   out[b, o*8+l] = sum_{i,k} X[b, i*8+k] * Wt[o*8+l, i*8+k] + bias[o*8+l]
//   Wt[(o,l),(i,k)] = sum_j cayley[j,k,l] * W[o,i,j]
// M=8192, N=2048, K=2048. bf16 MFMA, fp32 accumulate.
//
// R4 structure: R3 base (bf16 A pre-cast, global_load_lds width-16 staging,
// 128x128 tile, source-side XOR swizzle -> 0 bank conflicts, XCD band
// swizzle) + LDS DOUBLE-BUFFER at BK=32 with a SINGLE barrier per K-iter:
//   barrier; issue async loads for iter k+1 into buf^1; compute from buf.
// The vmcnt(0) drain the compiler emits before each s_barrier then applies
// to loads that have had a full compute phase (~170 cyc) in flight, instead
// of loads issued immediately before the drain (R3: full latency exposed).
// 32 KB total LDS keeps 5 blocks/CU (avoids the 64 KB occupancy cliff).

typedef __bf16 bf16x8 __attribute__((ext_vector_type(8)));
typedef float  f32x4  __attribute__((ext_vector_type(4)));

#define BM 128
#define BN 128
#define BK 32

__device__ __forceinline__ void async_copy16(void* lds_dst, const void* g_src) {
    // global -> LDS direct copy, 16B/lane; dest is wave-uniform base, HW
    // scatters lane i to base + i*16.
    __builtin_amdgcn_global_load_lds(
        (__attribute__((address_space(1))) void*)g_src,
        (__attribute__((address_space(3))) void*)lds_dst,
        16, 0, 0);
}

// ---------------- kernel 1: fp32 -> bf16 cast of X ----------------
__global__ __launch_bounds__(256) void cast_bf16_kernel(
    const float* __restrict__ in, __bf16* __restrict__ out, long n)
{
    long i = ((long)blockIdx.x * 256 + threadIdx.x) * 8;
    if (i + 8 <= n) {
        const f32x4* p = (const f32x4*)(in + i);
        f32x4 v0 = p[0];
        f32x4 v1 = p[1];
        bf16x8 o;
        o[0] = (__bf16)v0[0]; o[1] = (__bf16)v0[1];
        o[2] = (__bf16)v0[2]; o[3] = (__bf16)v0[3];
        o[4] = (__bf16)v1[0]; o[5] = (__bf16)v1[1];
        o[6] = (__bf16)v1[2]; o[7] = (__bf16)v1[3];
        *(bf16x8*)(out + i) = o;
    }
}

// ---------------- kernel 2: fold Cayley into weight ----------------
// Wt[n][kk] (bf16, [N][K]) with n=o*8+l, kk=i*8+k:
//   Wt = sum_j cayley[j*64 + k*8 + l] * W[o*Cin*8 + i*8 + j]
__global__ __launch_bounds__(256) void build_wt_kernel(
    const float* __restrict__ W,
    const float* __restrict__ cayley,
    __bf16* __restrict__ Wt,
    int Cin, int Cout)
{
    __shared__ float Cay[512];
    for (int t = threadIdx.x; t < 512; t += 256) Cay[t] = cayley[t];
    __syncthreads();

    int flat = blockIdx.x * 256 + threadIdx.x;   // flat = n*Cin + i
    int total = Cout * 8 * Cin;
    if (flat >= total) return;
    int i = flat % Cin;
    int n = flat / Cin;
    int o = n >> 3, l = n & 7;

    const float* wrow = W + ((size_t)o * Cin + i) * 8;
    float w8[8];
    #pragma unroll
    for (int j = 0; j < 8; ++j) w8[j] = wrow[j];

    bf16x8 outv;
    #pragma unroll
    for (int k = 0; k < 8; ++k) {
        float s = 0.f;
        #pragma unroll
        for (int j = 0; j < 8; ++j) s += Cay[j * 64 + k * 8 + l] * w8[j];
        outv[k] = (__bf16)s;
    }
    *(bf16x8*)(Wt + (size_t)n * (Cin * 8) + i * 8) = outv;
}

// ---------------- kernel 3: bf16 GEMM, C = A * Bt^T + bias ----------------
// A  : [M][K] bf16 (row-major, pre-cast)
// Bt : [N][K] bf16 (row-major)
// C  : [M][N] fp32
//
// LDS layout (A and B, per buffer): tile row = 32 bf16 = 4 groups of 8 bf16
// (16 B). Physical group p of row r holds GLOBAL group p ^ ((r>>1) & 3)
// (swizzle applied on the staging SOURCE address; global_load_lds lane
// scatter untouched). Fragment read for quad q, row l16:
//   physical offset (q ^ ((l16>>1) & 3)) * 8.
// Bank check: 16 lanes of a quad spread over 8 distinct 4-bank spans
// (4 swizzle keys x 2 row parities), 2 lanes/bank -> 2-way = free.
// R3 measured SQ_LDS_BANK_CONFLICT = 0 with this family of swizzles.
__global__ __launch_bounds__(256) void gemm_bt_kernel(
    const __bf16* __restrict__ A,
    const __bf16* __restrict__ Bt,
    const float*  __restrict__ bias,
    float* __restrict__ C,
    int M, int N, int K)
{
    __shared__ __align__(16) __bf16 As[2][BM * BK];  // 2 x 8 KB
    __shared__ __align__(16) __bf16 Bs[2][BN * BK];  // 2 x 8 KB

    const int tid  = threadIdx.x;
    const int wave = tid >> 6;
    const int lane = tid & 63;
    const int quad = lane >> 4;   // 0..3
    const int l16  = lane & 15;   // 0..15

    // --- XCD band swizzle: all 16 N-blocks of an M-band share bid%8 -> one XCD
    const int bid   = blockIdx.x;                    // 0..1023
    const int band  = (bid & 7) | ((bid >> 7) << 3); // 0..63
    const int ncol  = (bid >> 3) & 15;               // 0..15
    const int mBase = band * BM;
    const int nBase = ncol * BN;

    // --- staging: 1 KB chunk = 16 rows of 64 B; 8 chunks each for A and B;
    // wave w loads chunks 2w, 2w+1 of both. XOR swizzle on source group.
    const int srow = lane >> 2;                        // 0..15 row in chunk
    const int sgrp = (lane & 3) ^ ((srow >> 1) & 3);   // swizzled 16B-group

    const __bf16* gA0 = A  + (size_t)(mBase + (2 * wave + 0) * 16 + srow) * K + sgrp * 8;
    const __bf16* gA1 = A  + (size_t)(mBase + (2 * wave + 1) * 16 + srow) * K + sgrp * 8;
    const __bf16* gB0 = Bt + (size_t)(nBase + (2 * wave + 0) * 16 + srow) * K + sgrp * 8;
    const __bf16* gB1 = Bt + (size_t)(nBase + (2 * wave + 1) * 16 + srow) * K + sgrp * 8;
    const int cOff0 = (2 * wave + 0) * 512;   // 512 bf16 = 1 KB chunk
    const int cOff1 = (2 * wave + 1) * 512;

    // --- compute: wave quadrant (64x64), 4x4 grid of 16x16x32 MFMA tiles
    const int wm = (wave >> 1) * 64;
    const int wn = (wave & 1) * 64;
    const int offq = (quad ^ ((l16 >> 1) & 3)) * 8;  // swizzled frag offset
    const int rowA = (wm + l16) * BK;
    const int rowB = (wn + l16) * BK;

    f32x4 acc[4][4] = {};

    // --- prologue: stage k0 = 0 into buffer 0
    async_copy16(&As[0][cOff0], gA0);
    async_copy16(&As[0][cOff1], gA1);
    async_copy16(&Bs[0][cOff0], gB0);
    async_copy16(&Bs[0][cOff1], gB1);

    int buf = 0;
    for (int k0 = 0; k0 < K; k0 += BK) {
        // One barrier per iter. Compiler-emitted vmcnt(0) drain here applies
        // to loads issued one full compute phase ago. Also guarantees all
        // waves finished reading buf^1 (iter k-1's compute) before we
        // overwrite it below.
        __syncthreads();

        if (k0 + BK < K) {
            const int nb = buf ^ 1;
            async_copy16(&As[nb][cOff0], gA0 + k0 + BK);
            async_copy16(&As[nb][cOff1], gA1 + k0 + BK);
            async_copy16(&Bs[nb][cOff0], gB0 + k0 + BK);
            async_copy16(&Bs[nb][cOff1], gB1 + k0 + BK);
        }

        const __bf16* fA = &As[buf][rowA] + offq;
        const __bf16* fB = &Bs[buf][rowB] + offq;

        bf16x8 af[4], bfr[4];
        #pragma unroll
        for (int mt = 0; mt < 4; ++mt)
            af[mt] = *(const bf16x8*)(fA + mt * 16 * BK);
        #pragma unroll
        for (int nt = 0; nt < 4; ++nt)
            bfr[nt] = *(const bf16x8*)(fB + nt * 16 * BK);

        #pragma unroll
        for (int mt = 0; mt < 4; ++mt)
            #pragma unroll
            for (int nt = 0; nt < 4; ++nt)
                acc[mt][nt] = __builtin_amdgcn_mfma_f32_16x16x32_bf16(
                    af[mt], bfr[nt], acc[mt][nt], 0, 0, 0);

        buf ^= 1;
    }

    // --- epilogue: C/D layout col = lane&15, row = quad*4 + reg
    float bv[4];
    #pragma unroll
    for (int nt = 0; nt < 4; ++nt)
        bv[nt] = bias[nBase + wn + nt * 16 + l16];

    #pragma unroll
    for (int mt = 0; mt < 4; ++mt) {
        #pragma unroll
        for (int nt = 0; nt < 4; ++nt) {
            const int col = nBase + wn + nt * 16 + l16;
            #pragma unroll
            for (int r = 0; r < 4; ++r) {
                const int row = mBase + wm + mt * 16 + quad * 4 + r;
                C[(size_t)row * N + col] = acc[mt][nt][r] + bv[nt];
            }
        }
    }
}

extern "C" void kernel_launch(void* const* d_in, const int* in_sizes, int n_in,
                              void* d_out, int out_size, void* d_ws, size_t ws_size,
                              hipStream_t stream) {
    const float* x      = (const float*)d_in[0];  // [B][Cin][8]
    const float* weight = (const float*)d_in[1];  // [Cout][Cin][8]
    const float* bias   = (const float*)d_in[2];  // [Cout][8]
    const float* cayley = (const float*)d_in[3];  // [8][8][8]
    float* out = (float*)d_out;                   // [B][Cout][8]

    const int Cout = in_sizes[2] / 8;
    const int Cin  = in_sizes[1] / (Cout * 8);
    const int Bm   = in_sizes[0] / (Cin * 8);
    const int M = Bm;          // 8192
    const int N = Cout * 8;    // 2048
    const int K = Cin * 8;     // 2048

    __bf16* Xb = (__bf16*)d_ws;                               // M*K bf16 = 32 MB
    __bf16* Wt = (__bf16*)((char*)d_ws + (size_t)M * K * 2);  // N*K bf16 = 8 MB

    // 1) cast X to bf16
    long nx = (long)M * K;
    int castBlocks = (int)(nx / 8 / 256);   // nx divisible by 2048
    cast_bf16_kernel<<<castBlocks, 256, 0, stream>>>(x, Xb, nx);

    // 2) fold cayley into weight -> Wt [N][K] bf16
    int totalWt = N * Cin;
    build_wt_kernel<<<(totalWt + 255) / 256, 256, 0, stream>>>(weight, cayley, Wt, Cin, Cout);

    // 3) GEMM
    int grid = (M / BM) * (N / BN);   // 64 * 16 = 1024
    gemm_bt_kernel<<<grid, 256, 0, stream>>>(Xb, Wt, bias, out, M, N, K);
}

// Round 5
// 199.476 us; speedup vs baseline: 1.0402x; 1.0402x over previous
//
#include <hip/hip_runtime.h>
#include <stdint.h>
#include <stddef.h>

// CliffordLinear as one bf16 GEMM:
//   out[b, o*8+l] = sum_{i,k} X[b, i*8+k] * Wt[o*8+l, i*8+k] + bias[o*8+l]
//   Wt[(o,l),(i,k)] = sum_j cayley[j,k,l] * W[o,i,j]
// M=8192, N=2048, K=2048. bf16 MFMA, fp32 accumulate.
//
// R5 structure: software-pipelined LDS double buffer with STATICALLY DISTINCT
// buffers (As0/As1/Bs0/Bs1 as separate __shared__ objects, K-loop unrolled x2
// so every reference is a compile-time object). R4's runtime-indexed dbuf
// made LLVM treat the prefetch global_load_lds writes as possibly aliasing
// the current ds_reads -> conservative vmcnt(0) between issue and compute =
// full-latency serialization, worse than R3. Static objects remove that; the
// only drain is the barrier-top vmcnt(0), covering loads with a full compute
// phase in flight.
// Per phase: barrier; prefetch next tile into other buffer; compute this one.
// 32 KB LDS total -> 4-5 blocks/CU. Source-side XOR swizzle (R4-verified
// SQ_LDS_BANK_CONFLICT = 0), XCD band swizzle carried over.

typedef __bf16 bf16x8 __attribute__((ext_vector_type(8)));
typedef float  f32x4  __attribute__((ext_vector_type(4)));

#define BM 128
#define BN 128
#define BK 32

__device__ __forceinline__ void async_copy16(void* lds_dst, const void* g_src) {
    // global -> LDS direct copy, 16B/lane; dest is wave-uniform base, HW
    // scatters lane i to base + i*16.
    __builtin_amdgcn_global_load_lds(
        (__attribute__((address_space(1))) void*)g_src,
        (__attribute__((address_space(3))) void*)lds_dst,
        16, 0, 0);
}

// ---------------- kernel 1: fp32 -> bf16 cast of X ----------------
__global__ __launch_bounds__(256) void cast_bf16_kernel(
    const float* __restrict__ in, __bf16* __restrict__ out, long n)
{
    long i = ((long)blockIdx.x * 256 + threadIdx.x) * 8;
    if (i + 8 <= n) {
        const f32x4* p = (const f32x4*)(in + i);
        f32x4 v0 = p[0];
        f32x4 v1 = p[1];
        bf16x8 o;
        o[0] = (__bf16)v0[0]; o[1] = (__bf16)v0[1];
        o[2] = (__bf16)v0[2]; o[3] = (__bf16)v0[3];
        o[4] = (__bf16)v1[0]; o[5] = (__bf16)v1[1];
        o[6] = (__bf16)v1[2]; o[7] = (__bf16)v1[3];
        *(bf16x8*)(out + i) = o;
    }
}

// ---------------- kernel 2: fold Cayley into weight ----------------
// Wt[n][kk] (bf16, [N][K]) with n=o*8+l, kk=i*8+k:
//   Wt = sum_j cayley[j*64 + k*8 + l] * W[o*Cin*8 + i*8 + j]
__global__ __launch_bounds__(256) void build_wt_kernel(
    const float* __restrict__ W,
    const float* __restrict__ cayley,
    __bf16* __restrict__ Wt,
    int Cin, int Cout)
{
    __shared__ float Cay[512];
    for (int t = threadIdx.x; t < 512; t += 256) Cay[t] = cayley[t];
    __syncthreads();

    int flat = blockIdx.x * 256 + threadIdx.x;   // flat = n*Cin + i
    int total = Cout * 8 * Cin;
    if (flat >= total) return;
    int i = flat % Cin;
    int n = flat / Cin;
    int o = n >> 3, l = n & 7;

    const float* wrow = W + ((size_t)o * Cin + i) * 8;
    float w8[8];
    #pragma unroll
    for (int j = 0; j < 8; ++j) w8[j] = wrow[j];

    bf16x8 outv;
    #pragma unroll
    for (int k = 0; k < 8; ++k) {
        float s = 0.f;
        #pragma unroll
        for (int j = 0; j < 8; ++j) s += Cay[j * 64 + k * 8 + l] * w8[j];
        outv[k] = (__bf16)s;
    }
    *(bf16x8*)(Wt + (size_t)n * (Cin * 8) + i * 8) = outv;
}

// ---------------- kernel 3: bf16 GEMM, C = A * Bt^T + bias ----------------
// A  : [M][K] bf16 (row-major, pre-cast)
// Bt : [N][K] bf16 (row-major)
// C  : [M][N] fp32
//
// LDS layout (per buffer): tile row = 32 bf16 = 4 groups of 8 bf16 (16 B).
// Physical group p of row r holds GLOBAL group p ^ ((r>>1) & 3) (swizzle on
// the staging SOURCE address; global_load_lds lane scatter untouched).
// Fragment read: physical offset (quad ^ ((l16>>1) & 3)) * 8 -> 2-way bank
// aliasing (free). R4 measured SQ_LDS_BANK_CONFLICT = 0 with this swizzle.
__global__ __launch_bounds__(256) void gemm_bt_kernel(
    const __bf16* __restrict__ A,
    const __bf16* __restrict__ Bt,
    const float*  __restrict__ bias,
    float* __restrict__ C,
    int M, int N, int K)
{
    __shared__ __align__(16) __bf16 As0[BM * BK];  // 8 KB each
    __shared__ __align__(16) __bf16 As1[BM * BK];
    __shared__ __align__(16) __bf16 Bs0[BN * BK];
    __shared__ __align__(16) __bf16 Bs1[BN * BK];

    const int tid  = threadIdx.x;
    const int wave = tid >> 6;
    const int lane = tid & 63;
    const int quad = lane >> 4;   // 0..3
    const int l16  = lane & 15;   // 0..15

    // --- XCD band swizzle: all 16 N-blocks of an M-band share bid%8 -> one XCD
    const int bid   = blockIdx.x;                    // 0..1023
    const int band  = (bid & 7) | ((bid >> 7) << 3); // 0..63
    const int ncol  = (bid >> 3) & 15;               // 0..15
    const int mBase = band * BM;
    const int nBase = ncol * BN;

    // --- staging: 1 KB chunk = 16 rows of 64 B; 8 chunks per buffer for A/B;
    // wave w loads chunks 2w, 2w+1 of both. XOR swizzle on source group.
    const int srow = lane >> 2;                        // 0..15 row in chunk
    const int sgrp = (lane & 3) ^ ((srow >> 1) & 3);   // swizzled 16B-group

    const __bf16* gA0 = A  + (size_t)(mBase + (2 * wave + 0) * 16 + srow) * K + sgrp * 8;
    const __bf16* gA1 = A  + (size_t)(mBase + (2 * wave + 1) * 16 + srow) * K + sgrp * 8;
    const __bf16* gB0 = Bt + (size_t)(nBase + (2 * wave + 0) * 16 + srow) * K + sgrp * 8;
    const __bf16* gB1 = Bt + (size_t)(nBase + (2 * wave + 1) * 16 + srow) * K + sgrp * 8;
    const int cOff0 = (2 * wave + 0) * 512;   // 512 bf16 = 1 KB chunk
    const int cOff1 = (2 * wave + 1) * 512;

    // --- compute: wave quadrant (64x64), 4x4 grid of 16x16x32 MFMA tiles
    const int wm = (wave >> 1) * 64;
    const int wn = (wave & 1) * 64;
    const int offq = (quad ^ ((l16 >> 1) & 3)) * 8;  // swizzled frag offset
    const int rowA = (wm + l16) * BK;
    const int rowB = (wn + l16) * BK;

    f32x4 acc[4][4] = {};

#define PREFETCH(BUFA, BUFB, KOFF)                       \
    do {                                                 \
        async_copy16(&BUFA[cOff0], gA0 + (KOFF));        \
        async_copy16(&BUFA[cOff1], gA1 + (KOFF));        \
        async_copy16(&BUFB[cOff0], gB0 + (KOFF));        \
        async_copy16(&BUFB[cOff1], gB1 + (KOFF));        \
    } while (0)

#define COMPUTE(BUFA, BUFB)                                               \
    do {                                                                  \
        const __bf16* fA = &BUFA[rowA] + offq;                            \
        const __bf16* fB = &BUFB[rowB] + offq;                            \
        bf16x8 af[4], bfr[4];                                             \
        _Pragma("unroll")                                                 \
        for (int mt = 0; mt < 4; ++mt)                                    \
            af[mt] = *(const bf16x8*)(fA + mt * 16 * BK);                 \
        _Pragma("unroll")                                                 \
        for (int nt = 0; nt < 4; ++nt)                                    \
            bfr[nt] = *(const bf16x8*)(fB + nt * 16 * BK);                \
        _Pragma("unroll")                                                 \
        for (int mt = 0; mt < 4; ++mt)                                    \
            _Pragma("unroll")                                             \
            for (int nt = 0; nt < 4; ++nt)                                \
                acc[mt][nt] = __builtin_amdgcn_mfma_f32_16x16x32_bf16(    \
                    af[mt], bfr[nt], acc[mt][nt], 0, 0, 0);               \
    } while (0)

    // --- prologue: stage k=0 into buffer 0
    PREFETCH(As0, Bs0, 0);

    // --- main loop: 31 branch-free pairs; phase = barrier, prefetch other
    // buffer, compute this buffer. Barrier-top vmcnt(0) drain covers loads
    // issued one full compute phase earlier.
    int k0 = 0;
    for (; k0 < K - 2 * BK; k0 += 2 * BK) {
        __syncthreads();
        PREFETCH(As1, Bs1, k0 + BK);
        COMPUTE(As0, Bs0);

        __syncthreads();
        PREFETCH(As0, Bs0, k0 + 2 * BK);
        COMPUTE(As1, Bs1);
    }

    // --- tail pair (k0 == K - 64): last prefetch, then drain
    __syncthreads();
    PREFETCH(As1, Bs1, k0 + BK);
    COMPUTE(As0, Bs0);

    __syncthreads();
    COMPUTE(As1, Bs1);

#undef PREFETCH
#undef COMPUTE

    // --- epilogue: C/D layout col = lane&15, row = quad*4 + reg
    float bv[4];
    #pragma unroll
    for (int nt = 0; nt < 4; ++nt)
        bv[nt] = bias[nBase + wn + nt * 16 + l16];

    #pragma unroll
    for (int mt = 0; mt < 4; ++mt) {
        #pragma unroll
        for (int nt = 0; nt < 4; ++nt) {
            const int col = nBase + wn + nt * 16 + l16;
            #pragma unroll
            for (int r = 0; r < 4; ++r) {
                const int row = mBase + wm + mt * 16 + quad * 4 + r;
                C[(size_t)row * N + col] = acc[mt][nt][r] + bv[nt];
            }
        }
    }
}

extern "C" void kernel_launch(void* const* d_in, const int* in_sizes, int n_in,
                              void* d_out, int out_size, void* d_ws, size_t ws_size,
                              hipStream_t stream) {
    const float* x      = (const float*)d_in[0];  // [B][Cin][8]
    const float* weight = (const float*)d_in[1];  // [Cout][Cin][8]
    const float* bias   = (const float*)d_in[2];  // [Cout][8]
    const float* cayley = (const float*)d_in[3];  // [8][8][8]
    float* out = (float*)d_out;                   // [B][Cout][8]

    const int Cout = in_sizes[2] / 8;
    const int Cin  = in_sizes[1] / (Cout * 8);
    const int Bm   = in_sizes[0] / (Cin * 8);
    const int M = Bm;          // 8192
    const int N = Cout * 8;    // 2048
    const int K = Cin * 8;     // 2048

    __bf16* Xb = (__bf16*)d_ws;                               // M*K bf16 = 32 MB
    __bf16* Wt = (__bf16*)((char*)d_ws + (size_t)M * K * 2);  // N*K bf16 = 8 MB

    // 1) cast X to bf16
    long nx = (long)M * K;
    int castBlocks = (int)(nx / 8 / 256);   // nx divisible by 2048
    cast_bf16_kernel<<<castBlocks, 256, 0, stream>>>(x, Xb, nx);

    // 2) fold cayley into weight -> Wt [N][K] bf16
    int totalWt = N * Cin;
    build_wt_kernel<<<(totalWt + 255) / 256, 256, 0, stream>>>(weight, cayley, Wt, Cin, Cout);

    // 3) GEMM
    int grid = (M / BM) * (N / BN);   // 64 * 16 = 1024
    gemm_bt_kernel<<<grid, 256, 0, stream>>>(Xb, Wt, bias, out, M, N, K);
}